// Round 4
// baseline (584.691 us; speedup 1.0000x reference)
//
#include <hip/hip_runtime.h>
#include <hip/hip_bf16.h>

#define NN 50000
#define EE 800000

__device__ __forceinline__ float bflo(unsigned u) { return __uint_as_float(u << 16); }
__device__ __forceinline__ float bfhi(unsigned u) { return __uint_as_float(u & 0xffff0000u); }

// flag=1 if float tensors are bf16, 0 if f32 (proven mechanism from R3).
__global__ void detect_dtype(const unsigned* __restrict__ xw, int* __restrict__ flag) {
    if (threadIdx.x == 0 && blockIdx.x == 0) {
        int cnt = 0;
        for (int i = 0; i < 64; i++) {
            unsigned e = (xw[i] >> 7) & 0xFFu;
            if (e >= 100u && e <= 140u) cnt++;
        }
        *flag = (cnt >= 32) ? 1 : 0;
    }
}

__device__ __forceinline__ bool ei_is64(const int* __restrict__ ei) {
    const int oddor = ei[1] | ei[3] | ei[5] | ei[7] | ei[9] | ei[11] | ei[13] | ei[15];
    return oddor == 0;
}

// Phase 1: histogram of dst. 800K int HW atomics (vs 51.2M f32 CAS before).
__global__ __launch_bounds__(256) void hist_kernel(const int* __restrict__ ei,
                                                   int* __restrict__ counts) {
    const bool idx64 = ei_is64(ei);
    const long long* __restrict__ ei64 = (const long long*)ei;
    int e = blockIdx.x * 256 + threadIdx.x;
    if (e < EE) {
        int dst = idx64 ? (int)ei64[EE + e] : ei[EE + e];
        atomicAdd(&counts[dst], 1);
    }
}

// Phase 2: exclusive scan of counts -> offs (start) and cursor (running start).
__global__ __launch_bounds__(1024) void scan_kernel(const int* __restrict__ counts,
                                                    int* __restrict__ offs,
                                                    int* __restrict__ cursor) {
    __shared__ int part[1024];
    const int t = threadIdx.x;
    const int C = 49;                 // 1024*49 = 50176 >= NN
    const int base = t * C;
    int s = 0;
    for (int i = 0; i < C; i++) {
        int idx = base + i;
        if (idx < NN) s += counts[idx];
    }
    part[t] = s;
    __syncthreads();
    for (int off = 1; off < 1024; off <<= 1) {
        int add = (t >= off) ? part[t - off] : 0;
        __syncthreads();
        if (t >= off) part[t] += add;
        __syncthreads();
    }
    int running = part[t] - s;        // exclusive prefix of this thread's chunk
    for (int i = 0; i < C; i++) {
        int idx = base + i;
        if (idx < NN) {
            offs[idx]   = running;
            cursor[idx] = running;
            running += counts[idx];
        }
    }
}

// Phase 3: scatter edge ids into dst-sorted order. After this, cursor[n]=end[n].
__global__ __launch_bounds__(256) void scatter_kernel(const int* __restrict__ ei,
                                                      int* __restrict__ cursor,
                                                      int* __restrict__ perm) {
    const bool idx64 = ei_is64(ei);
    const long long* __restrict__ ei64 = (const long long*)ei;
    int e = blockIdx.x * 256 + threadIdx.x;
    if (e < EE) {
        int dst = idx64 ? (int)ei64[EE + e] : ei[EE + e];
        int pos = atomicAdd(&cursor[dst], 1);
        perm[pos] = e;
    }
}

// Phase 4: one wave per dst node — atomic-free gather-aggregate + fused MLP.
// Lane d owns feature d. We/W1/W2 columns register-resident (144 VGPR/lane).
// Per-wave LDS rows broadcast h and t; no __syncthreads needed (same-wave dep).
template <bool BF16>
__device__ __forceinline__ void gather_mlp_body(
    const void* __restrict__ xv, const int* __restrict__ ei,
    const void* __restrict__ eav,
    const void* __restrict__ Wev, const void* __restrict__ bev,
    const void* __restrict__ W1v, const void* __restrict__ b1v,
    const void* __restrict__ W2v, const void* __restrict__ b2v,
    const int* __restrict__ offs, const int* __restrict__ cursor,
    const int* __restrict__ perm, void* __restrict__ outv)
{
    __shared__ float sh[4][64];
    __shared__ float st[4][64];
    const int tid = threadIdx.x;
    const int d   = tid & 63;
    const int w   = tid >> 6;

    const bool idx64 = ei_is64(ei);
    const long long* __restrict__ ei64 = (const long long*)ei;

    float we[16], bed, w1c[64], w2c[64], b1d, b2d;
    if constexpr (BF16) {
        const __hip_bfloat16* We = (const __hip_bfloat16*)Wev;
        const __hip_bfloat16* W1 = (const __hip_bfloat16*)W1v;
        const __hip_bfloat16* W2 = (const __hip_bfloat16*)W2v;
#pragma unroll
        for (int k = 0; k < 16; k++) we[k] = __bfloat162float(We[k * 64 + d]);
#pragma unroll
        for (int k = 0; k < 64; k++) {
            w1c[k] = __bfloat162float(W1[k * 64 + d]);
            w2c[k] = __bfloat162float(W2[k * 64 + d]);
        }
        bed = __bfloat162float(((const __hip_bfloat16*)bev)[d]);
        b1d = __bfloat162float(((const __hip_bfloat16*)b1v)[d]);
        b2d = __bfloat162float(((const __hip_bfloat16*)b2v)[d]);
    } else {
        const float* We = (const float*)Wev;
        const float* W1 = (const float*)W1v;
        const float* W2 = (const float*)W2v;
#pragma unroll
        for (int k = 0; k < 16; k++) we[k] = We[k * 64 + d];
#pragma unroll
        for (int k = 0; k < 64; k++) {
            w1c[k] = W1[k * 64 + d];
            w2c[k] = W2[k * 64 + d];
        }
        bed = ((const float*)bev)[d];
        b1d = ((const float*)b1v)[d];
        b2d = ((const float*)b2v)[d];
    }

    const int nwaves = gridDim.x * 4;
    for (int node = blockIdx.x * 4 + w; node < NN; node += nwaves) {
        const int start = offs[node];
        const int end   = cursor[node];
        float acc = 0.0f;

        for (int base = start; base < end; base += 64) {
            int m = end - base;
            if (m > 64) m = 64;
            int e = 0, s = 0;
            if (d < m) {
                e = perm[base + d];
                s = idx64 ? (int)ei64[e] : ei[e];
            }
            for (int j = 0; j < m; j++) {
                const int ej = __shfl(e, j);
                const int sj = __shfl(s, j);

                float a[16];
                if constexpr (BF16) {
                    const uint4* row = (const uint4*)((const __hip_bfloat16*)eav + (size_t)ej * 16);
                    const uint4 p0 = row[0];
                    const uint4 p1 = row[1];
                    a[0]=bflo(p0.x); a[1]=bfhi(p0.x); a[2]=bflo(p0.y); a[3]=bfhi(p0.y);
                    a[4]=bflo(p0.z); a[5]=bfhi(p0.z); a[6]=bflo(p0.w); a[7]=bfhi(p0.w);
                    a[8]=bflo(p1.x); a[9]=bfhi(p1.x); a[10]=bflo(p1.y); a[11]=bfhi(p1.y);
                    a[12]=bflo(p1.z); a[13]=bfhi(p1.z); a[14]=bflo(p1.w); a[15]=bfhi(p1.w);
                } else {
                    const float4* row = (const float4*)((const float*)eav + (size_t)ej * 16);
                    const float4 q0 = row[0], q1 = row[1], q2 = row[2], q3 = row[3];
                    a[0]=q0.x; a[1]=q0.y; a[2]=q0.z; a[3]=q0.w;
                    a[4]=q1.x; a[5]=q1.y; a[6]=q1.z; a[7]=q1.w;
                    a[8]=q2.x; a[9]=q2.y; a[10]=q2.z; a[11]=q2.w;
                    a[12]=q3.x; a[13]=q3.y; a[14]=q3.z; a[15]=q3.w;
                }

                float macc = bed;
#pragma unroll
                for (int k = 0; k < 16; k++) macc = fmaf(a[k], we[k], macc);

                float xs;
                if constexpr (BF16) xs = __bfloat162float(((const __hip_bfloat16*)xv)[(size_t)sj * 64 + d]);
                else                xs = ((const float*)xv)[(size_t)sj * 64 + d];

                acc += fmaxf(macc + xs, 0.0f);
            }
        }

        float xn;
        if constexpr (BF16) xn = __bfloat162float(((const __hip_bfloat16*)xv)[(size_t)node * 64 + d]);
        else                xn = ((const float*)xv)[(size_t)node * 64 + d];
        sh[w][d] = xn + acc;           // same-wave LDS dep: no barrier needed

        float t = b1d;
        const float4* hv = (const float4*)sh[w];
#pragma unroll
        for (int k = 0; k < 16; k++) {
            const float4 hq = hv[k];
            t = fmaf(hq.x, w1c[4 * k],     t);
            t = fmaf(hq.y, w1c[4 * k + 1], t);
            t = fmaf(hq.z, w1c[4 * k + 2], t);
            t = fmaf(hq.w, w1c[4 * k + 3], t);
        }
        t = fmaxf(t, 0.0f);
        st[w][d] = t;

        float o = b2d;
        const float4* tv = (const float4*)st[w];
#pragma unroll
        for (int k = 0; k < 16; k++) {
            const float4 tq = tv[k];
            o = fmaf(tq.x, w2c[4 * k],     o);
            o = fmaf(tq.y, w2c[4 * k + 1], o);
            o = fmaf(tq.z, w2c[4 * k + 2], o);
            o = fmaf(tq.w, w2c[4 * k + 3], o);
        }
        if constexpr (BF16) ((__hip_bfloat16*)outv)[(size_t)node * 64 + d] = __float2bfloat16(o);
        else                ((float*)outv)[(size_t)node * 64 + d] = o;
    }
}

__global__ __launch_bounds__(256) void gather_mlp_kernel(
    const void* x, const int* ei, const void* ea,
    const void* We, const void* be,
    const void* W1, const void* b1, const void* W2, const void* b2,
    const int* offs, const int* cursor, const int* perm,
    void* out, const int* flag)
{
    if (*flag) gather_mlp_body<true >(x, ei, ea, We, be, W1, b1, W2, b2, offs, cursor, perm, out);
    else       gather_mlp_body<false>(x, ei, ea, We, be, W1, b1, W2, b2, offs, cursor, perm, out);
}

extern "C" void kernel_launch(void* const* d_in, const int* in_sizes, int n_in,
                              void* d_out, int out_size, void* d_ws, size_t ws_size,
                              hipStream_t stream) {
    const void* x          = d_in[0];
    const int*  edge_index = (const int*)d_in[1];
    const void* edge_attr  = d_in[2];
    const void* We         = d_in[3];
    const void* be         = d_in[4];
    const void* W1         = d_in[5];
    const void* b1         = d_in[6];
    const void* W2         = d_in[7];
    const void* b2         = d_in[8];

    // workspace: counts | offs | cursor | perm | flag  (~3.8 MB total)
    int* counts = (int*)d_ws;
    int* offs   = counts + 50016;
    int* cursor = offs   + 50016;
    int* perm   = cursor + 50016;
    int* flag   = perm   + EE;

    hipMemsetAsync(counts, 0, (size_t)NN * sizeof(int), stream);
    hipLaunchKernelGGL(detect_dtype, dim3(1), dim3(64), 0, stream,
                       (const unsigned*)x, flag);
    hipLaunchKernelGGL(hist_kernel, dim3((EE + 255) / 256), dim3(256), 0, stream,
                       edge_index, counts);
    hipLaunchKernelGGL(scan_kernel, dim3(1), dim3(1024), 0, stream,
                       counts, offs, cursor);
    hipLaunchKernelGGL(scatter_kernel, dim3((EE + 255) / 256), dim3(256), 0, stream,
                       edge_index, cursor, perm);
    hipLaunchKernelGGL(gather_mlp_kernel, dim3(1600), dim3(256), 0, stream,
                       x, edge_index, edge_attr, We, be, W1, b1, W2, b2,
                       offs, cursor, perm, d_out, flag);
}

// Round 5
// 324.552 us; speedup vs baseline: 1.8015x; 1.8015x over previous
//
#include <hip/hip_runtime.h>
#include <hip/hip_bf16.h>

#define NN 50000
#define EE 800000

__device__ __forceinline__ float bflo(unsigned u) { return __uint_as_float(u << 16); }
__device__ __forceinline__ float bfhi(unsigned u) { return __uint_as_float(u & 0xffff0000u); }

// flag=1 if float tensors are bf16, 0 if f32 (proven mechanism from R3).
__global__ void detect_dtype(const unsigned* __restrict__ xw, int* __restrict__ flag) {
    if (threadIdx.x == 0 && blockIdx.x == 0) {
        int cnt = 0;
        for (int i = 0; i < 64; i++) {
            unsigned e = (xw[i] >> 7) & 0xFFu;
            if (e >= 100u && e <= 140u) cnt++;
        }
        *flag = (cnt >= 32) ? 1 : 0;
    }
}

template <bool BF16>
__device__ __forceinline__ void edge_body(
    const void* __restrict__ xv, const int* __restrict__ ei,
    const void* __restrict__ eav, const void* __restrict__ Wev,
    const void* __restrict__ bev, float* __restrict__ agg)
{
    const int tid = threadIdx.x;
    const int d   = tid & 63;
    const int sub = tid >> 6;

    const int oddor = ei[1] | ei[3] | ei[5] | ei[7] | ei[9] | ei[11] | ei[13] | ei[15];
    const bool idx64 = (oddor == 0);
    const long long* __restrict__ ei64 = (const long long*)ei;

    float we[16];
    float bed;
    if constexpr (BF16) {
        const __hip_bfloat16* We = (const __hip_bfloat16*)Wev;
        const __hip_bfloat16* be = (const __hip_bfloat16*)bev;
#pragma unroll
        for (int k = 0; k < 16; k++) we[k] = __bfloat162float(We[k * 64 + d]);
        bed = __bfloat162float(be[d]);
    } else {
        const float* We = (const float*)Wev;
        const float* be = (const float*)bev;
#pragma unroll
        for (int k = 0; k < 16; k++) we[k] = We[k * 64 + d];
        bed = be[d];
    }

    const int stride = gridDim.x * 4;
    for (int e = blockIdx.x * 4 + sub; e < EE; e += stride) {
        int src, dst;
        if (idx64) { src = (int)ei64[e]; dst = (int)ei64[EE + e]; }
        else       { src = ei[e];        dst = ei[EE + e]; }

        float a[16];
        if constexpr (BF16) {
            const uint4* row = (const uint4*)((const __hip_bfloat16*)eav + (size_t)e * 16);
            const uint4 p0 = row[0];
            const uint4 p1 = row[1];
            a[0]=bflo(p0.x); a[1]=bfhi(p0.x); a[2]=bflo(p0.y); a[3]=bfhi(p0.y);
            a[4]=bflo(p0.z); a[5]=bfhi(p0.z); a[6]=bflo(p0.w); a[7]=bfhi(p0.w);
            a[8]=bflo(p1.x); a[9]=bfhi(p1.x); a[10]=bflo(p1.y); a[11]=bfhi(p1.y);
            a[12]=bflo(p1.z); a[13]=bfhi(p1.z); a[14]=bflo(p1.w); a[15]=bfhi(p1.w);
        } else {
            const float4* row = (const float4*)((const float*)eav + (size_t)e * 16);
            const float4 q0 = row[0], q1 = row[1], q2 = row[2], q3 = row[3];
            a[0]=q0.x; a[1]=q0.y; a[2]=q0.z; a[3]=q0.w;
            a[4]=q1.x; a[5]=q1.y; a[6]=q1.z; a[7]=q1.w;
            a[8]=q2.x; a[9]=q2.y; a[10]=q2.z; a[11]=q2.w;
            a[12]=q3.x; a[13]=q3.y; a[14]=q3.z; a[15]=q3.w;
        }

        float acc = bed;
#pragma unroll
        for (int k = 0; k < 16; k++) acc = fmaf(a[k], we[k], acc);

        float xs;
        if constexpr (BF16) xs = __bfloat162float(((const __hip_bfloat16*)xv)[(size_t)src * 64 + d]);
        else                xs = ((const float*)xv)[(size_t)src * 64 + d];

        float msg = fmaxf(acc + xs, 0.0f);
        // Native HW f32 atomic (global_atomic_add_f32): fire-and-forget, no
        // CAS read/retry round-trips. d_ws is coarse-grained device memory.
        unsafeAtomicAdd(&agg[(size_t)dst * 64 + d], msg);
    }
}

__global__ __launch_bounds__(256) void edge_agg_kernel(
    const void* x, const int* ei, const void* ea,
    const void* We, const void* be, float* agg, const int* flag)
{
    if (*flag) edge_body<true>(x, ei, ea, We, be, agg);
    else       edge_body<false>(x, ei, ea, We, be, agg);
}

template <bool BF16>
__device__ __forceinline__ void mlp_body(
    const void* __restrict__ xv, const float* __restrict__ agg,
    const void* __restrict__ W1v, const void* __restrict__ b1v,
    const void* __restrict__ W2v, const void* __restrict__ b2v,
    void* __restrict__ outv)
{
    __shared__ float sh[4][64];
    __shared__ float st[4][64];
    const int tid = threadIdx.x;
    const int d   = tid & 63;
    const int w   = tid >> 6;

    float w1c[64], w2c[64], b1d, b2d;
    if constexpr (BF16) {
        const __hip_bfloat16* W1 = (const __hip_bfloat16*)W1v;
        const __hip_bfloat16* W2 = (const __hip_bfloat16*)W2v;
#pragma unroll
        for (int k = 0; k < 64; k++) {
            w1c[k] = __bfloat162float(W1[k * 64 + d]);
            w2c[k] = __bfloat162float(W2[k * 64 + d]);
        }
        b1d = __bfloat162float(((const __hip_bfloat16*)b1v)[d]);
        b2d = __bfloat162float(((const __hip_bfloat16*)b2v)[d]);
    } else {
        const float* W1 = (const float*)W1v;
        const float* W2 = (const float*)W2v;
#pragma unroll
        for (int k = 0; k < 64; k++) {
            w1c[k] = W1[k * 64 + d];
            w2c[k] = W2[k * 64 + d];
        }
        b1d = ((const float*)b1v)[d];
        b2d = ((const float*)b2v)[d];
    }

    const int stride = gridDim.x * 4;
    const int iters  = (NN + stride - 1) / stride;
    int node = blockIdx.x * 4 + w;
    for (int it = 0; it < iters; it++, node += stride) {
        const bool valid = node < NN;
        if (valid) {
            float xs;
            if constexpr (BF16) xs = __bfloat162float(((const __hip_bfloat16*)xv)[(size_t)node * 64 + d]);
            else                xs = ((const float*)xv)[(size_t)node * 64 + d];
            sh[w][d] = xs + agg[(size_t)node * 64 + d];
        }
        __syncthreads();

        float t = b1d;
        const float4* hv = (const float4*)sh[w];
#pragma unroll
        for (int k = 0; k < 16; k++) {
            const float4 hq = hv[k];
            t = fmaf(hq.x, w1c[4 * k],     t);
            t = fmaf(hq.y, w1c[4 * k + 1], t);
            t = fmaf(hq.z, w1c[4 * k + 2], t);
            t = fmaf(hq.w, w1c[4 * k + 3], t);
        }
        t = fmaxf(t, 0.0f);
        st[w][d] = t;
        __syncthreads();

        float o = b2d;
        const float4* tv = (const float4*)st[w];
#pragma unroll
        for (int k = 0; k < 16; k++) {
            const float4 tq = tv[k];
            o = fmaf(tq.x, w2c[4 * k],     o);
            o = fmaf(tq.y, w2c[4 * k + 1], o);
            o = fmaf(tq.z, w2c[4 * k + 2], o);
            o = fmaf(tq.w, w2c[4 * k + 3], o);
        }
        if (valid) {
            if constexpr (BF16) ((__hip_bfloat16*)outv)[(size_t)node * 64 + d] = __float2bfloat16(o);
            else                ((float*)outv)[(size_t)node * 64 + d] = o;
        }
    }
}

__global__ __launch_bounds__(256) void mlp_kernel(
    const void* x, const float* agg,
    const void* W1, const void* b1, const void* W2, const void* b2,
    void* out, const int* flag)
{
    if (*flag) mlp_body<true>(x, agg, W1, b1, W2, b2, out);
    else       mlp_body<false>(x, agg, W1, b1, W2, b2, out);
}

extern "C" void kernel_launch(void* const* d_in, const int* in_sizes, int n_in,
                              void* d_out, int out_size, void* d_ws, size_t ws_size,
                              hipStream_t stream) {
    const void* x          = d_in[0];
    const int*  edge_index = (const int*)d_in[1];
    const void* edge_attr  = d_in[2];
    const void* We         = d_in[3];
    const void* be         = d_in[4];
    const void* W1         = d_in[5];
    const void* b1         = d_in[6];
    const void* W2         = d_in[7];
    const void* b2         = d_in[8];

    float* agg  = (float*)d_ws;                                   // NN*64 f32 = 12.8 MB
    int*   flag = (int*)((char*)d_ws + (size_t)NN * 64 * sizeof(float));

    hipMemsetAsync(agg, 0, (size_t)NN * 64 * sizeof(float), stream);
    hipLaunchKernelGGL(detect_dtype, dim3(1), dim3(64), 0, stream,
                       (const unsigned*)x, flag);
    hipLaunchKernelGGL(edge_agg_kernel, dim3(4096), dim3(256), 0, stream,
                       x, edge_index, edge_attr, We, be, agg, flag);
    hipLaunchKernelGGL(mlp_kernel, dim3(2048), dim3(256), 0, stream,
                       x, agg, W1, b1, W2, b2, d_out, flag);
}

// Round 6
// 309.237 us; speedup vs baseline: 1.8908x; 1.0495x over previous
//
#include <hip/hip_runtime.h>
#include <hip/hip_bf16.h>

#define NN 50000
#define EE 800000

__device__ __forceinline__ float bflo(unsigned u) { return __uint_as_float(u << 16); }
__device__ __forceinline__ float bfhi(unsigned u) { return __uint_as_float(u & 0xffff0000u); }

// flag=1 if float tensors are bf16, 0 if f32. Parallel version: 64 lanes,
// one load each, ballot (old 1-thread/64-serial-load version cost ~13us).
__global__ void detect_dtype(const unsigned* __restrict__ xw, int* __restrict__ flag) {
    const int t = threadIdx.x;  // 64 threads
    unsigned e = (xw[t] >> 7) & 0xFFu;
    unsigned long long m = __ballot(e >= 100u && e <= 140u);
    if (t == 0) *flag = (__popcll(m) >= 32) ? 1 : 0;
}

template <bool BF16>
__device__ __forceinline__ float edge_lin(const void* __restrict__ eav, int e,
                                          const float* __restrict__ we, float bed) {
    float acc = bed;
    if constexpr (BF16) {
        const uint4* row = (const uint4*)((const __hip_bfloat16*)eav + (size_t)e * 16);
        const uint4 p0 = row[0];
        const uint4 p1 = row[1];
        acc = fmaf(bflo(p0.x), we[0],  acc); acc = fmaf(bfhi(p0.x), we[1],  acc);
        acc = fmaf(bflo(p0.y), we[2],  acc); acc = fmaf(bfhi(p0.y), we[3],  acc);
        acc = fmaf(bflo(p0.z), we[4],  acc); acc = fmaf(bfhi(p0.z), we[5],  acc);
        acc = fmaf(bflo(p0.w), we[6],  acc); acc = fmaf(bfhi(p0.w), we[7],  acc);
        acc = fmaf(bflo(p1.x), we[8],  acc); acc = fmaf(bfhi(p1.x), we[9],  acc);
        acc = fmaf(bflo(p1.y), we[10], acc); acc = fmaf(bfhi(p1.y), we[11], acc);
        acc = fmaf(bflo(p1.z), we[12], acc); acc = fmaf(bfhi(p1.z), we[13], acc);
        acc = fmaf(bflo(p1.w), we[14], acc); acc = fmaf(bfhi(p1.w), we[15], acc);
    } else {
        const float4* row = (const float4*)((const float*)eav + (size_t)e * 16);
        const float4 q0 = row[0], q1 = row[1], q2 = row[2], q3 = row[3];
        acc = fmaf(q0.x, we[0],  acc); acc = fmaf(q0.y, we[1],  acc);
        acc = fmaf(q0.z, we[2],  acc); acc = fmaf(q0.w, we[3],  acc);
        acc = fmaf(q1.x, we[4],  acc); acc = fmaf(q1.y, we[5],  acc);
        acc = fmaf(q1.z, we[6],  acc); acc = fmaf(q1.w, we[7],  acc);
        acc = fmaf(q2.x, we[8],  acc); acc = fmaf(q2.y, we[9],  acc);
        acc = fmaf(q2.z, we[10], acc); acc = fmaf(q2.w, we[11], acc);
        acc = fmaf(q3.x, we[12], acc); acc = fmaf(q3.y, we[13], acc);
        acc = fmaf(q3.z, we[14], acc); acc = fmaf(q3.w, we[15], acc);
    }
    return acc;
}

// One wave per 4 contiguous edges per iteration: 4 independent load->gather->
// atomic chains in flight amortize the ~600-cycle latency chain that made the
// rolled loop run at 1 edge / 607 cycles (R5 counters).
template <bool BF16>
__device__ __forceinline__ void edge_body(
    const void* __restrict__ xv, const int* __restrict__ ei,
    const void* __restrict__ eav, const void* __restrict__ Wev,
    const void* __restrict__ bev, float* __restrict__ agg)
{
    const int tid = threadIdx.x;
    const int d   = tid & 63;
    const int sub = tid >> 6;

    const int oddor = ei[1] | ei[3] | ei[5] | ei[7] | ei[9] | ei[11] | ei[13] | ei[15];
    const bool idx64 = (oddor == 0);
    const long long* __restrict__ ei64 = (const long long*)ei;

    float we[16];
    float bed;
    if constexpr (BF16) {
        const __hip_bfloat16* We = (const __hip_bfloat16*)Wev;
#pragma unroll
        for (int k = 0; k < 16; k++) we[k] = __bfloat162float(We[k * 64 + d]);
        bed = __bfloat162float(((const __hip_bfloat16*)bev)[d]);
    } else {
        const float* We = (const float*)Wev;
#pragma unroll
        for (int k = 0; k < 16; k++) we[k] = We[k * 64 + d];
        bed = ((const float*)bev)[d];
    }

    const int wid = blockIdx.x * 4 + sub;
    const int nw  = gridDim.x * 4;
    // EE % 4 == 0: each 4-group is fully in range.
    for (int e0 = wid * 4; e0 < EE; e0 += nw * 4) {
        int src[4], dst[4];
        if (idx64) {
#pragma unroll
            for (int i = 0; i < 4; i++) {
                src[i] = (int)ei64[e0 + i];
                dst[i] = (int)ei64[EE + e0 + i];
            }
        } else {
            const int4 s4 = *(const int4*)(ei + e0);
            const int4 d4 = *(const int4*)(ei + EE + e0);
            src[0] = s4.x; src[1] = s4.y; src[2] = s4.z; src[3] = s4.w;
            dst[0] = d4.x; dst[1] = d4.y; dst[2] = d4.z; dst[3] = d4.w;
        }

        // 4 independent x-row gathers, issued before use.
        float xs[4];
#pragma unroll
        for (int i = 0; i < 4; i++) {
            if constexpr (BF16)
                xs[i] = __bfloat162float(((const __hip_bfloat16*)xv)[(size_t)src[i] * 64 + d]);
            else
                xs[i] = ((const float*)xv)[(size_t)src[i] * 64 + d];
        }

        float acc[4];
#pragma unroll
        for (int i = 0; i < 4; i++) acc[i] = edge_lin<BF16>(eav, e0 + i, we, bed);

#pragma unroll
        for (int i = 0; i < 4; i++) {
            float msg = fmaxf(acc[i] + xs[i], 0.0f);
            unsafeAtomicAdd(&agg[(size_t)dst[i] * 64 + d], msg);  // fire-and-forget
        }
    }
}

__global__ __launch_bounds__(256) void edge_agg_kernel(
    const void* x, const int* ei, const void* ea,
    const void* We, const void* be, float* agg, const int* flag)
{
    if (*flag) edge_body<true>(x, ei, ea, We, be, agg);
    else       edge_body<false>(x, ei, ea, We, be, agg);
}

template <bool BF16>
__device__ __forceinline__ void mlp_body(
    const void* __restrict__ xv, const float* __restrict__ agg,
    const void* __restrict__ W1v, const void* __restrict__ b1v,
    const void* __restrict__ W2v, const void* __restrict__ b2v,
    void* __restrict__ outv)
{
    __shared__ float sh[4][64];
    __shared__ float st[4][64];
    const int tid = threadIdx.x;
    const int d   = tid & 63;
    const int w   = tid >> 6;

    float w1c[64], w2c[64], b1d, b2d;
    if constexpr (BF16) {
        const __hip_bfloat16* W1 = (const __hip_bfloat16*)W1v;
        const __hip_bfloat16* W2 = (const __hip_bfloat16*)W2v;
#pragma unroll
        for (int k = 0; k < 64; k++) {
            w1c[k] = __bfloat162float(W1[k * 64 + d]);
            w2c[k] = __bfloat162float(W2[k * 64 + d]);
        }
        b1d = __bfloat162float(((const __hip_bfloat16*)b1v)[d]);
        b2d = __bfloat162float(((const __hip_bfloat16*)b2v)[d]);
    } else {
        const float* W1 = (const float*)W1v;
        const float* W2 = (const float*)W2v;
#pragma unroll
        for (int k = 0; k < 64; k++) {
            w1c[k] = W1[k * 64 + d];
            w2c[k] = W2[k * 64 + d];
        }
        b1d = ((const float*)b1v)[d];
        b2d = ((const float*)b2v)[d];
    }

    const int stride = gridDim.x * 4;
    // No __syncthreads anywhere: each wave only reads the LDS rows it wrote
    // (same-wave dep -> compiler's lgkmcnt wait suffices); waves run free.
    for (int node = blockIdx.x * 4 + w; node < NN; node += stride) {
        float xs;
        if constexpr (BF16) xs = __bfloat162float(((const __hip_bfloat16*)xv)[(size_t)node * 64 + d]);
        else                xs = ((const float*)xv)[(size_t)node * 64 + d];
        sh[w][d] = xs + agg[(size_t)node * 64 + d];

        float t = b1d;
        const float4* hv = (const float4*)sh[w];
#pragma unroll
        for (int k = 0; k < 16; k++) {
            const float4 hq = hv[k];
            t = fmaf(hq.x, w1c[4 * k],     t);
            t = fmaf(hq.y, w1c[4 * k + 1], t);
            t = fmaf(hq.z, w1c[4 * k + 2], t);
            t = fmaf(hq.w, w1c[4 * k + 3], t);
        }
        t = fmaxf(t, 0.0f);
        st[w][d] = t;

        float o = b2d;
        const float4* tv = (const float4*)st[w];
#pragma unroll
        for (int k = 0; k < 16; k++) {
            const float4 tq = tv[k];
            o = fmaf(tq.x, w2c[4 * k],     o);
            o = fmaf(tq.y, w2c[4 * k + 1], o);
            o = fmaf(tq.z, w2c[4 * k + 2], o);
            o = fmaf(tq.w, w2c[4 * k + 3], o);
        }
        if constexpr (BF16) ((__hip_bfloat16*)outv)[(size_t)node * 64 + d] = __float2bfloat16(o);
        else                ((float*)outv)[(size_t)node * 64 + d] = o;
    }
}

__global__ __launch_bounds__(256) void mlp_kernel(
    const void* x, const float* agg,
    const void* W1, const void* b1, const void* W2, const void* b2,
    void* out, const int* flag)
{
    if (*flag) mlp_body<true>(x, agg, W1, b1, W2, b2, out);
    else       mlp_body<false>(x, agg, W1, b1, W2, b2, out);
}

extern "C" void kernel_launch(void* const* d_in, const int* in_sizes, int n_in,
                              void* d_out, int out_size, void* d_ws, size_t ws_size,
                              hipStream_t stream) {
    const void* x          = d_in[0];
    const int*  edge_index = (const int*)d_in[1];
    const void* edge_attr  = d_in[2];
    const void* We         = d_in[3];
    const void* be         = d_in[4];
    const void* W1         = d_in[5];
    const void* b1         = d_in[6];
    const void* W2         = d_in[7];
    const void* b2         = d_in[8];

    float* agg  = (float*)d_ws;                                   // NN*64 f32 = 12.8 MB
    int*   flag = (int*)((char*)d_ws + (size_t)NN * 64 * sizeof(float));

    hipMemsetAsync(agg, 0, (size_t)NN * 64 * sizeof(float), stream);
    hipLaunchKernelGGL(detect_dtype, dim3(1), dim3(64), 0, stream,
                       (const unsigned*)x, flag);
    hipLaunchKernelGGL(edge_agg_kernel, dim3(4096), dim3(256), 0, stream,
                       x, edge_index, edge_attr, We, be, agg, flag);
    hipLaunchKernelGGL(mlp_kernel, dim3(2048), dim3(256), 0, stream,
                       x, agg, W1, b1, W2, b2, d_out, flag);
}